// Round 8
// baseline (383.911 us; speedup 1.0000x reference)
//
#include <hip/hip_runtime.h>

#define BATCH 1024
#define SEQ   144
#define DIM   192
#define NH    6
#define HD    32
#define SCALE 0.17677669529663687f   // 1/sqrt(32)
#define LOG2E 1.4426950408889634f

typedef __bf16 bf16x8 __attribute__((ext_vector_type(8)));
typedef __bf16 bf16x4 __attribute__((ext_vector_type(4)));
typedef float  f32x4  __attribute__((ext_vector_type(4)));

#if __has_builtin(__builtin_amdgcn_exp2f)
#define EXP2(v) __builtin_amdgcn_exp2f(v)
#else
#define EXP2(v) __expf((v) * 0.6931471805599453f)
#endif

// ---- workspace layout (bytes) ----
#define WS_W1T   0          // bf16 [576][192]  w1t[c][k] = w1[k][c] (*SCALE*LOG2E for c<192)
#define WS_W2T   221184     // bf16 [192][192]  w2t[n][k] = w2[k][n]
#define WS_B1S   294912     // f32  [576]       b1 (*SCALE*LOG2E for c<192)
#define WS_BM    297216     // bf16 [6][144][144]  bm[h][q][k] = (bias+mask)*LOG2E
#define WS_OPRE  546048     // bf16 [1024][144][192] pre-projection attention output

// ---------------------------------------------------------------------------
// Prep: transposed bf16 weights; log2e folded into q-scale and bias table.
// ---------------------------------------------------------------------------
__global__ __launch_bounds__(256) void k_prep(
        const float* __restrict__ w1, const float* __restrict__ w2,
        const float* __restrict__ b1, const float* __restrict__ bt,
        const int* __restrict__ pidx, const int* __restrict__ mask,
        char* __restrict__ ws) {
    __bf16* w1t = (__bf16*)(ws + WS_W1T);
    __bf16* w2t = (__bf16*)(ws + WS_W2T);
    float*  b1s = (float*)(ws + WS_B1S);
    __bf16* bm  = (__bf16*)(ws + WS_BM);
    const int blk = blockIdx.x, t = threadIdx.x;
    if (blk < 432) {                       // w1t
        int idx = blk * 256 + t;
        int k = idx / 576, c = idx % 576;
        float v = w1[idx] * (c < 192 ? SCALE * LOG2E : 1.0f);
        w1t[c * 192 + k] = (__bf16)v;
    } else if (blk < 576) {                // w2t
        int idx = (blk - 432) * 256 + t;
        int k = idx / 192, n = idx % 192;
        w2t[n * 192 + k] = (__bf16)w2[idx];
    } else if (blk < 657) {                // bm (pre-scaled by LOG2E)
        int idx = (blk - 576) * 256 + t;   // idx = q*144 + k
        int p = pidx[idx];
        float add = (mask[idx] == 0) ? -1e9f : 0.0f;
#pragma unroll
        for (int h = 0; h < NH; ++h)
            bm[h * 20736 + idx] = (__bf16)((bt[p * NH + h] + add) * LOG2E);
    } else {                               // b1s
        for (int c = t; c < 576; c += 256)
            b1s[c] = b1[c] * (c < 192 ? SCALE * LOG2E : 1.0f);
    }
}

// ---------------------------------------------------------------------------
// Fused QKV + attention. Block = (h, 8 b's); 9 waves; Ws staged once,
// FRAGMENT-LINEAR (zero-conflict b128 reads, immediate offsets).
// Phase-pipelined b-loop: P1(b+1) interleaved with P2P3(b); ONE barrier/iter.
// Q carried in registers across the overlap. Bias frags hoisted (b-invariant).
// P unnormalized; 1/sum applied to O via shfl. LDS 90880 B.
// ---------------------------------------------------------------------------
__global__ __launch_bounds__(576, 3) void k_attn(
        const float* __restrict__ x, char* __restrict__ ws) {
    const __bf16* w1t = (const __bf16*)(ws + WS_W1T);
    const float*  b1s = (const float*)(ws + WS_B1S);
    const __bf16* bmB = (const __bf16*)(ws + WS_BM);
    __bf16* opre = (__bf16*)(ws + WS_OPRE);

    __shared__ char smem[90880];
    __bf16* Ws  = (__bf16*)(smem);            // [36 frags][64 lanes][8] 36864B
    __bf16* Ks0 = (__bf16*)(smem + 36864);    // [144][40] dbuf
    __bf16* Ks1 = (__bf16*)(smem + 48384);
    __bf16* Vt0 = (__bf16*)(smem + 59904);    // [32][152] dbuf
    __bf16* Vt1 = (__bf16*)(smem + 69632);
    __bf16* Qs  = (__bf16*)(smem + 79360);    // [144][40] wave-private (Q / Pw / O)

    const int g  = blockIdx.x;                // 768 = 8 XCD x 96
    const int h  = (g >> 3) % 6;
    const int bg = (g & 7) + 8 * ((g >> 3) / 6);
    const int b0 = bg * 8;

    const int tid  = threadIdx.x;
    const int w    = tid >> 6;
    const int lane = tid & 63;
    const int lr   = tid & 15;
    const int lg   = lane >> 4;
    const int m0   = w * 16;
    const f32x4 zf = {0.f, 0.f, 0.f, 0.f};
    const bf16x8 zb = {(__bf16)0.f,(__bf16)0.f,(__bf16)0.f,(__bf16)0.f,
                       (__bf16)0.f,(__bf16)0.f,(__bf16)0.f,(__bf16)0.f};

    // ---- stage Ws fragment-linear: chunk c -> frag f=c>>6, lane ln=c&63
#pragma unroll
    for (int it = 0; it < 4; ++it) {
        int c = tid + it * 576;                // 2304 chunks of 16B
        int f = c >> 6, ln = c & 63;
        int n = f / 6, kk = f - n * 6;
        int flr = ln & 15, flg = ln >> 4;
        *(bf16x8*)&Ws[c * 8] = *(const bf16x8*)(w1t +
            (((n >> 1) * 192 + h * 32 + (n & 1) * 16 + flr) * 192 + kk * 32 + flg * 8));
    }

    // ---- hoisted bias fragments (identical for every b in this block)
    bf16x4 bb[9];
    {
        const __bf16* bmh = bmB + h * 20736 + (m0 + lr) * SEQ;
#pragma unroll
        for (int i = 0; i < 9; ++i) bb[i] = *(const bf16x4*)&bmh[i * 16 + lg * 4];
    }

    bf16x8 aX[6];
    f32x4  nx[12];

    auto xload = [&](int bidx) {
        const float* xr = x + ((size_t)bidx * SEQ + m0 + lr) * DIM + lg * 8;
#pragma unroll
        for (int q = 0; q < 6; ++q) {
            nx[2 * q]     = *(const f32x4*)(xr + q * 32);
            nx[2 * q + 1] = *(const f32x4*)(xr + q * 32 + 4);
        }
    };
    auto xcvt = [&]() {
#pragma unroll
        for (int kk = 0; kk < 6; ++kk) {
            f32x4 u = nx[2 * kk], v = nx[2 * kk + 1];
            bf16x8 t;
            t[0]=(__bf16)u[0]; t[1]=(__bf16)u[1]; t[2]=(__bf16)u[2]; t[3]=(__bf16)u[3];
            t[4]=(__bf16)v[0]; t[5]=(__bf16)v[1]; t[6]=(__bf16)v[2]; t[7]=(__bf16)v[3];
            aX[kk] = t;
        }
    };

    // P1: QKV projection for current aX -> KS/VT (+ Qs own strip)
    auto P1 = [&](__bf16* KS, __bf16* VT) {
        f32x4 acc[6];
#pragma unroll
        for (int n = 0; n < 6; ++n) acc[n] = zf;
#pragma unroll
        for (int kk = 0; kk < 6; ++kk)
#pragma unroll
            for (int n = 0; n < 6; ++n) {
                bf16x8 bF = *(bf16x8*)&Ws[((n * 6 + kk) * 64 + lane) * 8];
                acc[n] = __builtin_amdgcn_mfma_f32_16x16x32_bf16(aX[kk], bF, acc[n], 0, 0, 0);
            }
#pragma unroll
        for (int n = 0; n < 6; ++n) {
            int j = (n & 1) * 16 + lr;
            float bv = b1s[(n >> 1) * 192 + h * 32 + j];
            if (n < 2) {
#pragma unroll
                for (int r = 0; r < 4; ++r)
                    Qs[(m0 + lg * 4 + r) * 40 + j] = (__bf16)(acc[n][r] + bv);
            } else if (n < 4) {
#pragma unroll
                for (int r = 0; r < 4; ++r)
                    KS[(m0 + lg * 4 + r) * 40 + j] = (__bf16)(acc[n][r] + bv);
            } else {
                bf16x4 pk;
#pragma unroll
                for (int r = 0; r < 4; ++r) pk[r] = (__bf16)(acc[n][r] + bv);
                *(bf16x4*)&VT[j * 152 + m0 + lg * 4] = pk;   // [dim][key]
            }
        }
    };

    // P2+P3 for batch b using published KS/VT and register-carried qf
    auto P23 = [&](const __bf16* KS, const __bf16* VT, int b, bf16x8 qf) {
        f32x4 st[9];
#pragma unroll
        for (int i = 0; i < 9; ++i) {
            bf16x8 aF = *(bf16x8*)&KS[(i * 16 + lr) * 40 + lg * 8];
            st[i] = __builtin_amdgcn_mfma_f32_16x16x32_bf16(aF, qf, zf, 0, 0, 0);
        }
        float mx = -3.0e38f;
#pragma unroll
        for (int i = 0; i < 9; ++i)
#pragma unroll
            for (int r = 0; r < 4; ++r) {
                st[i][r] += (float)bb[i][r];
                mx = fmaxf(mx, st[i][r]);
            }
        mx = fmaxf(mx, __shfl_xor(mx, 16));
        mx = fmaxf(mx, __shfl_xor(mx, 32));
        float sum = 0.f;
#pragma unroll
        for (int i = 0; i < 9; ++i)
#pragma unroll
            for (int r = 0; r < 4; ++r) {
                float e = EXP2(st[i][r] - mx);   // log2e pre-folded upstream
                st[i][r] = e;
                sum += e;
            }
        sum += __shfl_xor(sum, 16);
        sum += __shfl_xor(sum, 32);
        float inv = 1.f / sum;

        __bf16* Pw = Qs + m0 * 40;               // [16][40] wave-private
        f32x4 o0 = zf, o1 = zf;
#pragma unroll
        for (int s = 0; s < 4; ++s) {
#pragma unroll
            for (int d = 0; d < 2; ++d) {
                int ii = 2 * s + d;
                bf16x4 pk;
#pragma unroll
                for (int r = 0; r < 4; ++r) pk[r] = (__bf16)st[ii][r];
                *(bf16x4*)&Pw[lr * 40 + d * 16 + lg * 4] = pk;
            }
            bf16x8 aP  = *(bf16x8*)&Pw[lr * 40 + lg * 8];
            bf16x8 v0F = *(bf16x8*)&VT[lr * 152 + s * 32 + lg * 8];
            bf16x8 v1F = *(bf16x8*)&VT[(16 + lr) * 152 + s * 32 + lg * 8];
            o0 = __builtin_amdgcn_mfma_f32_16x16x32_bf16(aP, v0F, o0, 0, 0, 0);
            o1 = __builtin_amdgcn_mfma_f32_16x16x32_bf16(aP, v1F, o1, 0, 0, 0);
        }
        {   // tail keys 128..143: lanes lg>=2 supply zeros
            bf16x4 pk;
#pragma unroll
            for (int r = 0; r < 4; ++r) pk[r] = (__bf16)st[8][r];
            *(bf16x4*)&Pw[lr * 40 + lg * 4] = pk;
            bf16x8 aP = zb, v0F = zb, v1F = zb;
            if (lg < 2) {
                aP  = *(bf16x8*)&Pw[lr * 40 + lg * 8];
                v0F = *(bf16x8*)&VT[lr * 152 + 128 + lg * 8];
                v1F = *(bf16x8*)&VT[(16 + lr) * 152 + 128 + lg * 8];
            }
            o0 = __builtin_amdgcn_mfma_f32_16x16x32_bf16(aP, v0F, o0, 0, 0, 0);
            o1 = __builtin_amdgcn_mfma_f32_16x16x32_bf16(aP, v1F, o1, 0, 0, 0);
        }
        // apply 1/sum (per query row, fetched cross-lane)
#pragma unroll
        for (int r = 0; r < 4; ++r) {
            float iv = __shfl(inv, lg * 4 + r);
            o0[r] *= iv;
            o1[r] *= iv;
        }
        // restage (coalesce) + store
#pragma unroll
        for (int r = 0; r < 4; ++r) {
            Pw[(lg * 4 + r) * 40 + lr]      = (__bf16)o0[r];
            Pw[(lg * 4 + r) * 40 + 16 + lr] = (__bf16)o1[r];
        }
        {
            int row = lane >> 2, c = lane & 3;
            bf16x8 ov = *(bf16x8*)&Pw[row * 40 + c * 8];
            *(bf16x8*)&opre[((size_t)b * SEQ + m0 + row) * DIM + h * HD + c * 8] = ov;
        }
    };

    // ---- prologue
    xload(b0);
    xcvt();                       // aX = X(b0)
    __syncthreads();              // Ws visible
    P1(Ks0, Vt0);                 // b0
    bf16x8 qf = *(bf16x8*)&Qs[(m0 + lr) * 40 + lg * 8];
    xload(b0 + 1);
    __syncthreads();              // publish Ks0/Vt0
    xcvt();                       // aX = X(b1)

    // ---- pipelined main loop: P1(b+1) || P2P3(b), one barrier per iter
#pragma unroll 2
    for (int nb = 0; nb < 8; ++nb) {
        __bf16* Ksc = (nb & 1) ? Ks1 : Ks0;
        __bf16* Vtc = (nb & 1) ? Vt1 : Vt0;
        __bf16* Ksn = (nb & 1) ? Ks0 : Ks1;
        __bf16* Vtn = (nb & 1) ? Vt0 : Vt1;
        bf16x8 qf_next;
        if (nb < 7) {
            P1(Ksn, Vtn);                                   // b_{nb+1}
            qf_next = *(bf16x8*)&Qs[(m0 + lr) * 40 + lg * 8];
            if (nb < 6) xload(b0 + nb + 2);
        }
        P23(Ksc, Vtc, b0 + nb, qf);
        if (nb < 7) {
            qf = qf_next;
            if (nb < 6) xcvt();
            __syncthreads();
        }
    }
}

// ---------------------------------------------------------------------------
// Out-projection (proven R7 design): W2 in registers, M-loop, dbuf A-staging.
// ---------------------------------------------------------------------------
__global__ __launch_bounds__(256, 3) void k_proj(
        const char* __restrict__ ws, const float* __restrict__ b2,
        float* __restrict__ out) {
    const __bf16* opre = (const __bf16*)(ws + WS_OPRE);
    const __bf16* w2t  = (const __bf16*)(ws + WS_W2T);
    __shared__ __bf16 As[2][16 * 200];

    const int tid = threadIdx.x;
    const int w = tid >> 6, lr = tid & 15, lg = (tid & 63) >> 4;
    const f32x4 zf = {0.f, 0.f, 0.f, 0.f};

    bf16x8 bW[3][6];
    float bcol[3];
#pragma unroll
    for (int i = 0; i < 3; ++i) {
        int col = (w * 3 + i) * 16 + lr;
        bcol[i] = b2[col];
#pragma unroll
        for (int kk = 0; kk < 6; ++kk)
            bW[i][kk] = *(const bf16x8*)(w2t + (col * 192 + kk * 32 + lg * 8));
    }

    const int i0r = tid / 24,  i0c = tid % 24;
    const int i1r = (tid + 256) / 24, i1c = (tid + 256) % 24;
    const bool has1 = tid < 128;

    {
        size_t row0 = (size_t)blockIdx.x * 9 * 16;
        bf16x8 s0 = *(const bf16x8*)&opre[(row0 + i0r) * DIM + i0c * 8];
        *(bf16x8*)&As[0][i0r * 200 + i0c * 8] = s0;
        if (has1) {
            bf16x8 s1 = *(const bf16x8*)&opre[(row0 + i1r) * DIM + i1c * 8];
            *(bf16x8*)&As[0][i1r * 200 + i1c * 8] = s1;
        }
    }

    for (int t = 0; t < 9; ++t) {
        bf16x8 n0, n1;
        if (t < 8) {
            size_t rown = ((size_t)blockIdx.x * 9 + t + 1) * 16;
            n0 = *(const bf16x8*)&opre[(rown + i0r) * DIM + i0c * 8];
            if (has1) n1 = *(const bf16x8*)&opre[(rown + i1r) * DIM + i1c * 8];
        }
        __syncthreads();
        const __bf16* A = As[t & 1];
        f32x4 acc[3];
#pragma unroll
        for (int i = 0; i < 3; ++i) acc[i] = zf;
#pragma unroll
        for (int kk = 0; kk < 6; ++kk) {
            bf16x8 aF = *(const bf16x8*)&A[lr * 200 + kk * 32 + lg * 8];
#pragma unroll
            for (int i = 0; i < 3; ++i)
                acc[i] = __builtin_amdgcn_mfma_f32_16x16x32_bf16(aF, bW[i][kk], acc[i], 0, 0, 0);
        }
        size_t row0 = ((size_t)blockIdx.x * 9 + t) * 16;
#pragma unroll
        for (int i = 0; i < 3; ++i) {
            int col = (w * 3 + i) * 16 + lr;
#pragma unroll
            for (int r = 0; r < 4; ++r)
                out[(row0 + lg * 4 + r) * DIM + col] = acc[i][r] + bcol[i];
        }
        if (t < 8) {
            *(bf16x8*)&As[(t + 1) & 1][i0r * 200 + i0c * 8] = n0;
            if (has1) *(bf16x8*)&As[(t + 1) & 1][i1r * 200 + i1c * 8] = n1;
        }
    }
}

// ---------------------------------------------------------------------------
extern "C" void kernel_launch(void* const* d_in, const int* in_sizes, int n_in,
                              void* d_out, int out_size, void* d_ws, size_t ws_size,
                              hipStream_t stream) {
    const float* x    = (const float*)d_in[0];
    const float* w1   = (const float*)d_in[1];
    const float* b1   = (const float*)d_in[2];
    const float* w2   = (const float*)d_in[3];
    const float* b2   = (const float*)d_in[4];
    const float* bt   = (const float*)d_in[5];
    const int*   pidx = (const int*)d_in[6];
    const int*   mask = (const int*)d_in[7];
    float* out = (float*)d_out;
    char*  ws  = (char*)d_ws;

    k_prep<<<658, 256, 0, stream>>>(w1, w2, b1, bt, pidx, mask, ws);
    k_attn<<<768, 576, 0, stream>>>(x, ws);
    k_proj<<<1024, 256, 0, stream>>>(ws, b2, out);
}

// Round 9
// 235.938 us; speedup vs baseline: 1.6272x; 1.6272x over previous
//
#include <hip/hip_runtime.h>

#define BATCH 1024
#define SEQ   144
#define DIM   192
#define NH    6
#define HD    32
#define SCALE 0.17677669529663687f   // 1/sqrt(32)

typedef __bf16 bf16x8 __attribute__((ext_vector_type(8)));
typedef __bf16 bf16x4 __attribute__((ext_vector_type(4)));
typedef float  f32x4  __attribute__((ext_vector_type(4)));

// LDS-only barrier: drains LDS ops (lgkmcnt) but lets global loads/stores
// stay in flight across the barrier (avoids the vmcnt(0) drain that
// __syncthreads emits). Guards: all inter-wave communication here is via
// ds_write -> barrier -> ds_read, which lgkmcnt(0)+s_barrier fully orders.
__device__ __forceinline__ void lds_barrier() {
    __builtin_amdgcn_sched_barrier(0);
    asm volatile("s_waitcnt lgkmcnt(0)" ::: "memory");
    __builtin_amdgcn_s_barrier();
    __builtin_amdgcn_sched_barrier(0);
}

// ---- workspace layout (bytes) ----
#define WS_W1T   0          // bf16 [576][192]  w1t[c][k] = w1[k][c] (*SCALE for c<192)
#define WS_W2T   221184     // bf16 [192][192]  w2t[n][k] = w2[k][n]
#define WS_B1S   294912     // f32  [576]       b1 (*SCALE for c<192)
#define WS_BM    297216     // bf16 [6][144][144]  bm[h][query][key] = bias + mask
#define WS_OPRE  546048     // bf16 [1024][144][192] pre-projection attention output

// ---------------------------------------------------------------------------
// Prep: transpose/convert weights to bf16 B^T layout, build bf16 bias+mask.
// ---------------------------------------------------------------------------
__global__ __launch_bounds__(256) void k_prep(
        const float* __restrict__ w1, const float* __restrict__ w2,
        const float* __restrict__ b1, const float* __restrict__ bt,
        const int* __restrict__ pidx, const int* __restrict__ mask,
        char* __restrict__ ws) {
    __bf16* w1t = (__bf16*)(ws + WS_W1T);
    __bf16* w2t = (__bf16*)(ws + WS_W2T);
    float*  b1s = (float*)(ws + WS_B1S);
    __bf16* bm  = (__bf16*)(ws + WS_BM);
    const int blk = blockIdx.x, t = threadIdx.x;
    if (blk < 432) {                       // w1t: 110592 elems
        int idx = blk * 256 + t;
        int k = idx / 576, c = idx % 576;
        float v = w1[idx] * (c < 192 ? SCALE : 1.0f);
        w1t[c * 192 + k] = (__bf16)v;
    } else if (blk < 576) {                // w2t: 36864 elems
        int idx = (blk - 432) * 256 + t;
        int k = idx / 192, n = idx % 192;
        w2t[n * 192 + k] = (__bf16)w2[idx];
    } else if (blk < 657) {                // bm: 20736 (query,key) pairs
        int idx = (blk - 576) * 256 + t;   // idx = query*144 + key
        int p = pidx[idx];
        float add = (mask[idx] == 0) ? -1e9f : 0.0f;
#pragma unroll
        for (int h = 0; h < NH; ++h)
            bm[h * 20736 + idx] = (__bf16)(bt[p * NH + h] + add);
    } else {                               // b1s
        for (int c = t; c < 576; c += 256)
            b1s[c] = b1[c] * (c < 192 ? SCALE : 1.0f);
    }
}

// ---------------------------------------------------------------------------
// Fused QKV + attention. Block = fixed head h, 8 consecutive b's.
// Grid 768 = 8 XCD x 96. Ws staged ONCE per block, FRAGMENT-LINEAR
// ([36 frags][64 lanes][16B] -> conflict-free b128 reads). Ks/Vt dbuf ->
// ONE LDS-only barrier per b (global loads/stores stay in flight across it).
// X[b+1] prefetched into regs during b's P2/P3. LDS 90880 B.
// ---------------------------------------------------------------------------
__global__ __launch_bounds__(576, 3) void k_attn(
        const float* __restrict__ x, char* __restrict__ ws) {
    const __bf16* w1t = (const __bf16*)(ws + WS_W1T);
    const float*  b1s = (const float*)(ws + WS_B1S);
    const __bf16* bmB = (const __bf16*)(ws + WS_BM);
    __bf16* opre = (__bf16*)(ws + WS_OPRE);

    __shared__ char smem[90880];
    __bf16* Ws  = (__bf16*)(smem);             // [36][64][8]  36864B (once)
    __bf16* Ks0 = (__bf16*)(smem + 36864);     // [144][40]  x2 dbuf
    __bf16* Ks1 = (__bf16*)(smem + 48384);
    __bf16* Vt0 = (__bf16*)(smem + 59904);     // [32][152]  x2 dbuf
    __bf16* Vt1 = (__bf16*)(smem + 69632);
    __bf16* Qs  = (__bf16*)(smem + 79360);     // [144][40]  wave-private

    const int g  = blockIdx.x;
    const int h  = (g >> 3) % 6;
    const int bg = (g & 7) + 8 * ((g >> 3) / 6);
    const int b0 = bg * 8;

    const int tid  = threadIdx.x;
    const int w    = tid >> 6;
    const int lane = tid & 63;
    const int lr   = tid & 15;
    const int lg   = lane >> 4;
    const int m0   = w * 16;
    const f32x4 zf = {0.f, 0.f, 0.f, 0.f};
    const bf16x8 zb = {(__bf16)0.f,(__bf16)0.f,(__bf16)0.f,(__bf16)0.f,
                       (__bf16)0.f,(__bf16)0.f,(__bf16)0.f,(__bf16)0.f};

    // ---- stage Ws fragment-linear: chunk c -> frag f=c>>6, lane ln=c&63
#pragma unroll
    for (int it = 0; it < 4; ++it) {
        int c = tid + it * 576;                // 2304 chunks of 16B
        int f = c >> 6, ln = c & 63;
        int n = f / 6, kk = f - n * 6;
        int flr = ln & 15, flg = ln >> 4;
        *(bf16x8*)&Ws[c * 8] = *(const bf16x8*)(w1t +
            (((n >> 1) * 192 + h * 32 + (n & 1) * 16 + flr) * 192 + kk * 32 + flg * 8));
    }

    // ---- prologue: X[b0] strip -> aX fragments
    bf16x8 aX[6];
    {
        const float* xr = x + ((size_t)b0 * SEQ + m0 + lr) * DIM + lg * 8;
#pragma unroll
        for (int kk = 0; kk < 6; ++kk) {
            f32x4 u = *(const f32x4*)(xr + kk * 32);
            f32x4 v = *(const f32x4*)(xr + kk * 32 + 4);
            bf16x8 t;
            t[0]=(__bf16)u[0]; t[1]=(__bf16)u[1]; t[2]=(__bf16)u[2]; t[3]=(__bf16)u[3];
            t[4]=(__bf16)v[0]; t[5]=(__bf16)v[1]; t[6]=(__bf16)v[2]; t[7]=(__bf16)v[3];
            aX[kk] = t;
        }
    }
    lds_barrier();   // Ws visible

    const __bf16* bmh = bmB + h * 20736 + (m0 + lr) * SEQ;
    const float*  b1h = b1s;

#pragma unroll 2
    for (int nb = 0; nb < 8; ++nb) {
        const int b = b0 + nb;
        __bf16* Ks = (nb & 1) ? Ks1 : Ks0;
        __bf16* Vt = (nb & 1) ? Vt1 : Vt0;

        // ---- P1: Y[strip][96] = X @ W1_h^T  (B-frags from LDS, conflict-free)
        f32x4 acc[6];
#pragma unroll
        for (int n = 0; n < 6; ++n) acc[n] = zf;
#pragma unroll
        for (int kk = 0; kk < 6; ++kk)
#pragma unroll
            for (int n = 0; n < 6; ++n) {
                bf16x8 bF = *(bf16x8*)&Ws[((n * 6 + kk) * 64 + lane) * 8];
                acc[n] = __builtin_amdgcn_mfma_f32_16x16x32_bf16(aX[kk], bF, acc[n], 0, 0, 0);
            }

        // ---- issue X[b+1] prefetch (raw f32; convert at loop end)
        f32x4 nx[12];
        if (nb < 7) {
            const float* xr = x + ((size_t)(b + 1) * SEQ + m0 + lr) * DIM + lg * 8;
#pragma unroll
            for (int q = 0; q < 6; ++q) {
                nx[2 * q]     = *(const f32x4*)(xr + q * 32);
                nx[2 * q + 1] = *(const f32x4*)(xr + q * 32 + 4);
            }
        }

        // ---- bias prefetch (L2)
        bf16x4 bb[9];
#pragma unroll
        for (int i = 0; i < 9; ++i) bb[i] = *(const bf16x4*)&bmh[i * 16 + lg * 4];

        // ---- scatter Q/K/Vt (+b1)
#pragma unroll
        for (int n = 0; n < 6; ++n) {
            int j = (n & 1) * 16 + lr;
            float bv = b1h[(n >> 1) * 192 + h * 32 + j];
            if (n < 2) {
#pragma unroll
                for (int r = 0; r < 4; ++r)
                    Qs[(m0 + lg * 4 + r) * 40 + j] = (__bf16)(acc[n][r] + bv);
            } else if (n < 4) {
#pragma unroll
                for (int r = 0; r < 4; ++r)
                    Ks[(m0 + lg * 4 + r) * 40 + j] = (__bf16)(acc[n][r] + bv);
            } else {
                bf16x4 pk;
#pragma unroll
                for (int r = 0; r < 4; ++r) pk[r] = (__bf16)(acc[n][r] + bv);
                *(bf16x4*)&Vt[j * 152 + m0 + lg * 4] = pk;   // [dim][key]
            }
        }
        lds_barrier();   // the ONE barrier per b (LDS-only drain)

        // ---- P2: S^T = mfma(K,Q); +bias; in-register softmax
        f32x4 st[9];
        {
            bf16x8 qF = *(bf16x8*)&Qs[(m0 + lr) * 40 + lg * 8];
#pragma unroll
            for (int i = 0; i < 9; ++i) {
                bf16x8 aF = *(bf16x8*)&Ks[(i * 16 + lr) * 40 + lg * 8];
                st[i] = __builtin_amdgcn_mfma_f32_16x16x32_bf16(aF, qF, zf, 0, 0, 0);
            }
            float mx = -3.0e38f;
#pragma unroll
            for (int i = 0; i < 9; ++i)
#pragma unroll
                for (int r = 0; r < 4; ++r) {
                    st[i][r] += (float)bb[i][r];
                    mx = fmaxf(mx, st[i][r]);
                }
            mx = fmaxf(mx, __shfl_xor(mx, 16));
            mx = fmaxf(mx, __shfl_xor(mx, 32));
            float sum = 0.f;
#pragma unroll
            for (int i = 0; i < 9; ++i)
#pragma unroll
                for (int r = 0; r < 4; ++r) {
                    float e = __expf(st[i][r] - mx);
                    st[i][r] = e;
                    sum += e;
                }
            sum += __shfl_xor(sum, 16);
            sum += __shfl_xor(sum, 32);
            float inv = 1.f / sum;
#pragma unroll
            for (int i = 0; i < 9; ++i)
#pragma unroll
                for (int r = 0; r < 4; ++r) st[i][r] *= inv;
        }

        // ---- P3: O = P @ V via per-wave P scratch (overlay on Qs strip)
        __bf16* Pw = Qs + m0 * 40;     // [16][40] wave-private
        f32x4 o0 = zf, o1 = zf;
#pragma unroll
        for (int s = 0; s < 4; ++s) {
#pragma unroll
            for (int d = 0; d < 2; ++d) {
                int ii = 2 * s + d;
                bf16x4 pk;
#pragma unroll
                for (int r = 0; r < 4; ++r) pk[r] = (__bf16)st[ii][r];
                *(bf16x4*)&Pw[lr * 40 + d * 16 + lg * 4] = pk;
            }
            bf16x8 aP  = *(bf16x8*)&Pw[lr * 40 + lg * 8];
            bf16x8 v0F = *(bf16x8*)&Vt[lr * 152 + s * 32 + lg * 8];
            bf16x8 v1F = *(bf16x8*)&Vt[(16 + lr) * 152 + s * 32 + lg * 8];
            o0 = __builtin_amdgcn_mfma_f32_16x16x32_bf16(aP, v0F, o0, 0, 0, 0);
            o1 = __builtin_amdgcn_mfma_f32_16x16x32_bf16(aP, v1F, o1, 0, 0, 0);
        }
        {   // tail keys 128..143: lanes lg>=2 supply zeros
            bf16x4 pk;
#pragma unroll
            for (int r = 0; r < 4; ++r) pk[r] = (__bf16)st[8][r];
            *(bf16x4*)&Pw[lr * 40 + lg * 4] = pk;
            bf16x8 aP = zb, v0F = zb, v1F = zb;
            if (lg < 2) {
                aP  = *(bf16x8*)&Pw[lr * 40 + lg * 8];
                v0F = *(bf16x8*)&Vt[lr * 152 + 128 + lg * 8];
                v1F = *(bf16x8*)&Vt[(16 + lr) * 152 + 128 + lg * 8];
            }
            o0 = __builtin_amdgcn_mfma_f32_16x16x32_bf16(aP, v0F, o0, 0, 0, 0);
            o1 = __builtin_amdgcn_mfma_f32_16x16x32_bf16(aP, v1F, o1, 0, 0, 0);
        }

        // ---- O restage (coalesce) + store to opre[b][m][h*32..]
#pragma unroll
        for (int r = 0; r < 4; ++r) {
            Pw[(lg * 4 + r) * 40 + lr]      = (__bf16)o0[r];
            Pw[(lg * 4 + r) * 40 + 16 + lr] = (__bf16)o1[r];
        }
        {
            int row = lane >> 2, c = lane & 3;
            bf16x8 ov = *(bf16x8*)&Pw[row * 40 + c * 8];
            *(bf16x8*)&opre[((size_t)b * SEQ + m0 + row) * DIM + h * HD + c * 8] = ov;
        }

        // ---- convert prefetched X -> aX
        if (nb < 7) {
#pragma unroll
            for (int kk = 0; kk < 6; ++kk) {
                f32x4 u = nx[2 * kk], v = nx[2 * kk + 1];
                bf16x8 t;
                t[0]=(__bf16)u[0]; t[1]=(__bf16)u[1]; t[2]=(__bf16)u[2]; t[3]=(__bf16)u[3];
                t[4]=(__bf16)v[0]; t[5]=(__bf16)v[1]; t[6]=(__bf16)v[2]; t[7]=(__bf16)v[3];
                aX[kk] = t;
            }
        }
    }
}

// ---------------------------------------------------------------------------
// Out-projection (R7 design): W2 in registers, M-loop, dbuf A-staging,
// LDS-only barriers (prefetch loads stay in flight).
// ---------------------------------------------------------------------------
__global__ __launch_bounds__(256, 3) void k_proj(
        const char* __restrict__ ws, const float* __restrict__ b2,
        float* __restrict__ out) {
    const __bf16* opre = (const __bf16*)(ws + WS_OPRE);
    const __bf16* w2t  = (const __bf16*)(ws + WS_W2T);
    __shared__ __bf16 As[2][16 * 200];

    const int tid = threadIdx.x;
    const int w = tid >> 6, lr = tid & 15, lg = (tid & 63) >> 4;
    const f32x4 zf = {0.f, 0.f, 0.f, 0.f};

    bf16x8 bW[3][6];
    float bcol[3];
#pragma unroll
    for (int i = 0; i < 3; ++i) {
        int col = (w * 3 + i) * 16 + lr;
        bcol[i] = b2[col];
#pragma unroll
        for (int kk = 0; kk < 6; ++kk)
            bW[i][kk] = *(const bf16x8*)(w2t + (col * 192 + kk * 32 + lg * 8));
    }

    const int i0r = tid / 24,  i0c = tid % 24;
    const int i1r = (tid + 256) / 24, i1c = (tid + 256) % 24;
    const bool has1 = tid < 128;

    {
        size_t row0 = (size_t)blockIdx.x * 9 * 16;
        bf16x8 s0 = *(const bf16x8*)&opre[(row0 + i0r) * DIM + i0c * 8];
        *(bf16x8*)&As[0][i0r * 200 + i0c * 8] = s0;
        if (has1) {
            bf16x8 s1 = *(const bf16x8*)&opre[(row0 + i1r) * DIM + i1c * 8];
            *(bf16x8*)&As[0][i1r * 200 + i1c * 8] = s1;
        }
    }

    for (int t = 0; t < 9; ++t) {
        bf16x8 n0, n1;
        if (t < 8) {
            size_t rown = ((size_t)blockIdx.x * 9 + t + 1) * 16;
            n0 = *(const bf16x8*)&opre[(rown + i0r) * DIM + i0c * 8];
            if (has1) n1 = *(const bf16x8*)&opre[(rown + i1r) * DIM + i1c * 8];
        }
        lds_barrier();   // As[t&1] ds_writes visible; global loads stay in flight
        const __bf16* A = As[t & 1];
        f32x4 acc[3];
#pragma unroll
        for (int i = 0; i < 3; ++i) acc[i] = zf;
#pragma unroll
        for (int kk = 0; kk < 6; ++kk) {
            bf16x8 aF = *(const bf16x8*)&A[lr * 200 + kk * 32 + lg * 8];
#pragma unroll
            for (int i = 0; i < 3; ++i)
                acc[i] = __builtin_amdgcn_mfma_f32_16x16x32_bf16(aF, bW[i][kk], acc[i], 0, 0, 0);
        }
        size_t row0 = ((size_t)blockIdx.x * 9 + t) * 16;
#pragma unroll
        for (int i = 0; i < 3; ++i) {
            int col = (w * 3 + i) * 16 + lr;
#pragma unroll
            for (int r = 0; r < 4; ++r)
                out[(row0 + lg * 4 + r) * DIM + col] = acc[i][r] + bcol[i];
        }
        if (t < 8) {
            *(bf16x8*)&As[(t + 1) & 1][i0r * 200 + i0c * 8] = n0;
            if (has1) *(bf16x8*)&As[(t + 1) & 1][i1r * 200 + i1c * 8] = n1;
        }
    }
}

// ---------------------------------------------------------------------------
extern "C" void kernel_launch(void* const* d_in, const int* in_sizes, int n_in,
                              void* d_out, int out_size, void* d_ws, size_t ws_size,
                              hipStream_t stream) {
    const float* x    = (const float*)d_in[0];
    const float* w1   = (const float*)d_in[1];
    const float* b1   = (const float*)d_in[2];
    const float* w2   = (const float*)d_in[3];
    const float* b2   = (const float*)d_in[4];
    const float* bt   = (const float*)d_in[5];
    const int*   pidx = (const int*)d_in[6];
    const int*   mask = (const int*)d_in[7];
    float* out = (float*)d_out;
    char*  ws  = (char*)d_ws;

    k_prep<<<658, 256, 0, stream>>>(w1, w2, b1, bt, pidx, mask, ws);
    k_attn<<<768, 576, 0, stream>>>(x, ws);
    k_proj<<<1024, 256, 0, stream>>>(ws, b2, out);
}